// Round 5
// baseline (101.276 us; speedup 1.0000x reference)
//
#include <hip/hip_runtime.h>
#include <hip/hip_bf16.h>
#include <math.h>

// Problem constants
#define BB 8
#define SS 2048
#define DD 256
#define FF 8
#define NTOK (BB*SS)   // 16384

typedef __bf16 bf16x8 __attribute__((ext_vector_type(8)));
typedef float  f32x4  __attribute__((ext_vector_type(4)));
typedef float  f32x2  __attribute__((ext_vector_type(2)));

// ---------------- Kernel A: h = tanh(x @ W1^T + b1) -> fp8(e4m3) table via MFMA ----------
// Tile: BM=64 tokens x BN=64 outputs, 256 threads (4 waves), grid 1024 = 4 blocks/CU.
// W1 band held in REGISTERS (16 bf16x8 frags/wave, loaded once) -> no B-side LDS at all.
// K=256 in 4 steps of BK=64, double-buffered x-LDS, ONE barrier per step.
// XCD swizzle: 4 n-siblings of a token group differ by 256 in bx -> same XCD, x L2-local.
#define BM 64
#define BN 64
#define BK 64
#define NSTEP (DD/BK)   // 4
#define XS 72           // x-LDS row stride in ushorts (BK + 8 pad): 144 B, 16B-aligned

__device__ __forceinline__ float fast_tanh(float x) {
    float e = __expf(2.0f * x);
    return 1.0f - 2.0f * __builtin_amdgcn_rcpf(e + 1.0f);
}

__device__ __forceinline__ unsigned pack2_bf16(float a, float b) {
    return (__float_as_uint(a) >> 16) | (__float_as_uint(b) & 0xFFFF0000u);
}

__device__ __forceinline__ unsigned char f32_to_fp8(float v) {
    return (unsigned char)(__builtin_amdgcn_cvt_pk_fp8_f32(v, v, 0, false) & 0xFF);
}

__global__ __launch_bounds__(256, 4) void gemm_tanh_kernel(
    const float* __restrict__ x, const float* __restrict__ W1,
    const float* __restrict__ b1, unsigned char* __restrict__ table)
{
    __shared__ __align__(16) unsigned short xs[2][BM * XS];   // 18.4 KB (reused as fp8 scratch)

    const int tid  = threadIdx.x;
    const int bx   = blockIdx.x;
    const int tokgrp = bx & 255;          // siblings (same x-tile) differ by 256 -> same XCD
    const int nblk   = bx >> 8;
    const int tok0 = tokgrp * BM;
    const int n0   = nblk * BN;

    // re-zero padding row 0 (256 fp8 bytes); ws is re-poisoned before every launch
    if (bx == 0 && tid < 64) ((unsigned int*)table)[tid] = 0u;

    const int wave = tid >> 6, lane = tid & 63;
    const int wm = wave >> 1;        // 0..1: 32-row m band
    const int wn = wave & 1;         // 0..1: 32-col n band
    const int lr = lane & 15;
    const int kg = lane >> 4;

    // ---- one-time W1 band preload into registers: bfrg[kc][nf] covers k=kc*32+kg*8..+8 ----
    bf16x8 bfrg[8][2];
    #pragma unroll
    for (int kc = 0; kc < 8; ++kc) {
        #pragma unroll
        for (int nf = 0; nf < 2; ++nf) {
            int n = n0 + wn * 32 + nf * 16 + lr;
            const float* p = &W1[(size_t)n * DD + kc * 32 + kg * 8];
            f32x4 lo = *(const f32x4*)p;
            f32x4 hi = *(const f32x4*)(p + 4);
            uint4 pk;
            pk.x = pack2_bf16(lo.x, lo.y);
            pk.y = pack2_bf16(lo.z, lo.w);
            pk.z = pack2_bf16(hi.x, hi.y);
            pk.w = pack2_bf16(hi.z, hi.w);
            bfrg[kc][nf] = __builtin_bit_cast(bf16x8, pk);
        }
    }

    f32x4 xr[4];                     // x staging registers

    auto load_chunk = [&](int k0) {
        #pragma unroll
        for (int rep = 0; rep < 4; ++rep) {            // x: 64 rows x 16 f32x4 = 1024 slots
            int slot = rep * 256 + tid;
            int row = slot >> 4, kc = slot & 15;
            xr[rep] = *(const f32x4*)&x[(size_t)(tok0 + row) * DD + k0 + kc * 4];
        }
    };
    auto store_lds = [&](int buf) {
        #pragma unroll
        for (int rep = 0; rep < 4; ++rep) {
            int slot = rep * 256 + tid;
            int row = slot >> 4, kc = slot & 15;
            uint2 p;
            p.x = pack2_bf16(xr[rep].x, xr[rep].y);
            p.y = pack2_bf16(xr[rep].z, xr[rep].w);
            *(uint2*)&xs[buf][row * XS + kc * 4] = p;
        }
    };

    f32x4 acc[2][2];
    #pragma unroll
    for (int mf = 0; mf < 2; ++mf)
        #pragma unroll
        for (int nf = 0; nf < 2; ++nf)
            acc[mf][nf] = (f32x4){0.f, 0.f, 0.f, 0.f};

    load_chunk(0);
    store_lds(0);

    #pragma unroll
    for (int s = 0; s < NSTEP; ++s) {
        __syncthreads();                               // one barrier per step
        const int buf = s & 1;
        if (s + 1 < NSTEP) load_chunk((s + 1) * BK);   // next global loads in flight early

        bf16x8 af[2][2];                               // [k-chunk][mf]
        #pragma unroll
        for (int c = 0; c < 2; ++c)
            #pragma unroll
            for (int mf = 0; mf < 2; ++mf) {
                int m = wm * 32 + mf * 16 + lr;
                af[c][mf] = *(const bf16x8*)&xs[buf][m * XS + c * 32 + kg * 8];
            }
        if (s + 1 < NSTEP) store_lds(buf ^ 1);         // buf^1 reads drained at this barrier

        #pragma unroll
        for (int c = 0; c < 2; ++c)
            #pragma unroll
            for (int mf = 0; mf < 2; ++mf)
                #pragma unroll
                for (int nf = 0; nf < 2; ++nf)
                    acc[mf][nf] = __builtin_amdgcn_mfma_f32_16x16x32_bf16(
                        af[c][mf], bfrg[s * 2 + c][nf], acc[mf][nf], 0, 0, 0);
    }

    // ---- epilogue: bias + tanh -> fp8, LDS transpose, coalesced uint4 stores ----
    float bj[2];
    #pragma unroll
    for (int nf = 0; nf < 2; ++nf) bj[nf] = b1[n0 + wn * 32 + nf * 16 + lr];

    __syncthreads();                                   // safe to reuse xs as scratch
    unsigned char* sc = (unsigned char*)&xs[0][0];     // [BM][80] fp8 scratch (5.1 KB)
    #pragma unroll
    for (int mf = 0; mf < 2; ++mf) {
        #pragma unroll
        for (int r = 0; r < 4; ++r) {
            int m = wm * 32 + mf * 16 + kg * 4 + r;    // C/D layout: col=lane&15, row=kg*4+reg
            #pragma unroll
            for (int nf = 0; nf < 2; ++nf) {
                float v = fast_tanh(acc[mf][nf][r] + bj[nf]);
                sc[m * 80 + wn * 32 + nf * 16 + lr] = f32_to_fp8(v);
            }
        }
    }
    __syncthreads();
    {
        int row = tid >> 2;                            // 64 rows x 64 B, 16 B per thread
        int off = (tid & 3) * 16;
        uint4 v = *(const uint4*)&sc[row * 80 + off];
        *(uint4*)&table[(size_t)(1 + tok0 + row) * DD + n0 + off] = v;
    }
}

// ---------------- Kernel B: fp8 gather + max over F + dot(w2) + bias + mask ----------------
// One wave per token. Halves of the wave take alternating f-rows; uint2 (8 fp8) per lane.
// (Unchanged from round 4 to cleanly attribute this round's delta to kernel A.)
__global__ __launch_bounds__(256) void gather_score_kernel(
    const unsigned char* __restrict__ table,
    const int* __restrict__ select_idx,
    const int* __restrict__ word_mask,
    const float* __restrict__ w2,
    const float* __restrict__ b2,
    float* __restrict__ out)
{
    const int tid  = threadIdx.x;
    const int lane = tid & 63;
    const int wv   = tid >> 6;
    const int i    = blockIdx.x * 4 + wv;    // token
    const int half = lane >> 5;
    const int c    = lane & 31;
    const int d0   = c * 8;                  // 8 dims (8 B) per lane

    const int4* sp = (const int4*)(select_idx + (size_t)i * FF);
    int4 q0 = sp[0], q1 = sp[1];
    int rows[4];
    rows[0] = half ? q0.y : q0.x;
    rows[1] = half ? q0.w : q0.z;
    rows[2] = half ? q1.y : q1.x;
    rows[3] = half ? q1.w : q1.z;

    float m[8];
    #pragma unroll
    for (int j = 0; j < 8; ++j) m[j] = -INFINITY;

    #pragma unroll
    for (int it = 0; it < 4; ++it) {
        uint2 u = *(const uint2*)(table + (size_t)rows[it] * DD + d0);
        f32x2 a0 = __builtin_amdgcn_cvt_pk_f32_fp8(u.x, false);
        f32x2 a1 = __builtin_amdgcn_cvt_pk_f32_fp8(u.x, true);
        f32x2 a2 = __builtin_amdgcn_cvt_pk_f32_fp8(u.y, false);
        f32x2 a3 = __builtin_amdgcn_cvt_pk_f32_fp8(u.y, true);
        m[0] = fmaxf(m[0], a0.x); m[1] = fmaxf(m[1], a0.y);
        m[2] = fmaxf(m[2], a1.x); m[3] = fmaxf(m[3], a1.y);
        m[4] = fmaxf(m[4], a2.x); m[5] = fmaxf(m[5], a2.y);
        m[6] = fmaxf(m[6], a3.x); m[7] = fmaxf(m[7], a3.y);
    }

    #pragma unroll
    for (int j = 0; j < 8; ++j) m[j] = fmaxf(m[j], __shfl_xor(m[j], 32));

    f32x4 wa = *(const f32x4*)&w2[d0];
    f32x4 wb = *(const f32x4*)&w2[d0 + 4];
    float p = m[0] * wa.x + m[1] * wa.y + m[2] * wa.z + m[3] * wa.w
            + m[4] * wb.x + m[5] * wb.y + m[6] * wb.z + m[7] * wb.w;

    #pragma unroll
    for (int off = 16; off; off >>= 1) p += __shfl_xor(p, off);

    if (lane == 0) {
        float neg = word_mask[i] ? 0.f : -10000.f;
        out[i] = p + b2[0] + neg;
    }
}

extern "C" void kernel_launch(void* const* d_in, const int* in_sizes, int n_in,
                              void* d_out, int out_size, void* d_ws, size_t ws_size,
                              hipStream_t stream) {
    const float* hs    = (const float*)d_in[0];   // [B,S,D] f32
    const int*   sidx  = (const int*)  d_in[1];   // [B,S,F] i32
    const int*   wmask = (const int*)  d_in[2];   // [B,S]   i32
    const float* W1    = (const float*)d_in[3];   // [D,D]   f32
    const float* b1    = (const float*)d_in[4];   // [D]     f32
    const float* w2    = (const float*)d_in[5];   // [D]     f32
    const float* b2    = (const float*)d_in[6];   // [1]     f32
    float* out = (float*)d_out;                   // [B,S]   f32

    unsigned char* table = (unsigned char*)d_ws;  // [1+NTOK, D] fp8 e4m3 (~4.2 MB)

    gemm_tanh_kernel<<<(NTOK / BM) * (DD / BN), 256, 0, stream>>>(hs, W1, b1, table);
    gather_score_kernel<<<NTOK / 4, 256, 0, stream>>>(table, sidx, wmask, w2, b2, out);
}

// Round 6
// 88.364 us; speedup vs baseline: 1.1461x; 1.1461x over previous
//
#include <hip/hip_runtime.h>
#include <hip/hip_bf16.h>
#include <math.h>

// Problem constants
#define BB 8
#define SS 2048
#define DD 256
#define FF 8
#define NTOK (BB*SS)   // 16384

typedef __bf16 bf16x8 __attribute__((ext_vector_type(8)));
typedef float  f32x4  __attribute__((ext_vector_type(4)));
typedef float  f32x2  __attribute__((ext_vector_type(2)));

// ---------------- Kernel A: h = tanh(x @ W1^T + b1) -> fp8(e4m3) table via MFMA ----------
// R4 structure (proven 85.8): BM=128 x BN=64, 512 threads (8 waves), grid 512 = 2 blocks/CU.
// NEW: W1 band staged into LDS ONCE before the K-loop (bf16, stride 264 ushorts -> 2-way
// bank aliasing only). K-loop stages x only: 4 global loads + 4 LDS stores/step.
#define BM 128
#define BN 64
#define BK 64
#define NSTEP (DD/BK)   // 4
#define XS 72           // x-LDS row stride in ushorts (BK + 8 pad): 144 B, 16B-aligned
#define WS 264          // W1-LDS row stride in ushorts (DD + 8 pad): 528 B = 132 dwords (mod 32 = 4)

__device__ __forceinline__ float fast_tanh(float x) {
    float e = __expf(2.0f * x);
    return 1.0f - 2.0f * __builtin_amdgcn_rcpf(e + 1.0f);
}

__device__ __forceinline__ unsigned pack2_bf16(float a, float b) {
    return (__float_as_uint(a) >> 16) | (__float_as_uint(b) & 0xFFFF0000u);
}

__device__ __forceinline__ unsigned char f32_to_fp8(float v) {
    return (unsigned char)(__builtin_amdgcn_cvt_pk_fp8_f32(v, v, 0, false) & 0xFF);
}

__global__ __launch_bounds__(512, 4) void gemm_tanh_kernel(
    const float* __restrict__ x, const float* __restrict__ W1,
    const float* __restrict__ b1, unsigned char* __restrict__ table)
{
    __shared__ __align__(16) unsigned short xs[2][BM * XS];   // 36.9 KB (reused as fp8 scratch)
    __shared__ __align__(16) unsigned short wlds[BN * WS];    // 33.8 KB, staged once

    const int tid  = threadIdx.x;
    const int bx   = blockIdx.x;
    const int tokgrp = bx & 127;          // the 4 n-siblings of a token group share an XCD
    const int nblk   = bx >> 7;
    const int tok0 = tokgrp * BM;
    const int n0   = nblk * BN;

    // re-zero padding row 0 (256 fp8 bytes); ws is re-poisoned before every launch
    if (bx == 0 && tid < 64) ((unsigned int*)table)[tid] = 0u;

    const int wave = tid >> 6, lane = tid & 63;
    const int wm = wave >> 1;        // 0..3: 32-row m band
    const int wn = wave & 1;         // 0..1: 32-col n band
    const int lr = lane & 15;
    const int kg = lane >> 4;

    // ---- one-time W1 band -> LDS (bf16): 64 rows x 256 k = 4096 f32x4 slots ----
    {
        #pragma unroll
        for (int rep = 0; rep < 8; ++rep) {
            int slot = rep * 512 + tid;
            int row = slot >> 6, kc = slot & 63;
            f32x4 w = *(const f32x4*)&W1[(size_t)(n0 + row) * DD + kc * 4];
            uint2 p;
            p.x = pack2_bf16(w.x, w.y);
            p.y = pack2_bf16(w.z, w.w);
            *(uint2*)&wlds[row * WS + kc * 4] = p;
        }
    }

    f32x4 xr[4];                     // x staging registers

    auto load_chunk = [&](int k0) {
        #pragma unroll
        for (int rep = 0; rep < 4; ++rep) {            // x: 128 rows x 16 f32x4 = 2048 slots
            int slot = rep * 512 + tid;
            int row = slot >> 4, kc = slot & 15;
            xr[rep] = *(const f32x4*)&x[(size_t)(tok0 + row) * DD + k0 + kc * 4];
        }
    };
    auto store_lds = [&](int buf) {
        #pragma unroll
        for (int rep = 0; rep < 4; ++rep) {
            int slot = rep * 512 + tid;
            int row = slot >> 4, kc = slot & 15;
            uint2 p;
            p.x = pack2_bf16(xr[rep].x, xr[rep].y);
            p.y = pack2_bf16(xr[rep].z, xr[rep].w);
            *(uint2*)&xs[buf][row * XS + kc * 4] = p;
        }
    };

    f32x4 acc[2][2];
    #pragma unroll
    for (int mf = 0; mf < 2; ++mf)
        #pragma unroll
        for (int nf = 0; nf < 2; ++nf)
            acc[mf][nf] = (f32x4){0.f, 0.f, 0.f, 0.f};

    load_chunk(0);
    store_lds(0);

    for (int s = 0; s < NSTEP; ++s) {
        __syncthreads();                               // one barrier per step
        const int buf = s & 1;
        if (s + 1 < NSTEP) load_chunk((s + 1) * BK);   // next x loads in flight early

        bf16x8 af[2][2], bfr[2][2];                    // [k-chunk][frag]
        #pragma unroll
        for (int c = 0; c < 2; ++c) {
            #pragma unroll
            for (int mf = 0; mf < 2; ++mf) {
                int m = wm * 32 + mf * 16 + lr;
                af[c][mf] = *(const bf16x8*)&xs[buf][m * XS + c * 32 + kg * 8];
            }
            #pragma unroll
            for (int nf = 0; nf < 2; ++nf) {
                int n = wn * 32 + nf * 16 + lr;
                bfr[c][nf] = *(const bf16x8*)&wlds[n * WS + s * BK + c * 32 + kg * 8];
            }
        }
        if (s + 1 < NSTEP) store_lds(buf ^ 1);         // buf^1 reads drained at this barrier

        #pragma unroll
        for (int c = 0; c < 2; ++c)
            #pragma unroll
            for (int mf = 0; mf < 2; ++mf)
                #pragma unroll
                for (int nf = 0; nf < 2; ++nf)
                    acc[mf][nf] = __builtin_amdgcn_mfma_f32_16x16x32_bf16(
                        af[c][mf], bfr[c][nf], acc[mf][nf], 0, 0, 0);
    }

    // ---- epilogue: bias + tanh -> fp8, LDS transpose, coalesced uint4 stores ----
    float bj[2];
    #pragma unroll
    for (int nf = 0; nf < 2; ++nf) bj[nf] = b1[n0 + wn * 32 + nf * 16 + lr];

    __syncthreads();                                   // safe to reuse xs as scratch
    unsigned char* sc = (unsigned char*)&xs[0][0];     // [BM][80] fp8 scratch (10 KB)
    #pragma unroll
    for (int mf = 0; mf < 2; ++mf) {
        #pragma unroll
        for (int r = 0; r < 4; ++r) {
            int m = wm * 32 + mf * 16 + kg * 4 + r;    // C/D layout: col=lane&15, row=kg*4+reg
            #pragma unroll
            for (int nf = 0; nf < 2; ++nf) {
                float v = fast_tanh(acc[mf][nf][r] + bj[nf]);
                sc[m * 80 + wn * 32 + nf * 16 + lr] = f32_to_fp8(v);
            }
        }
    }
    __syncthreads();
    {
        int row = tid >> 2;                            // 128 rows x 64 B, 16 B per thread
        int off = (tid & 3) * 16;
        uint4 v = *(const uint4*)&sc[row * 80 + off];
        *(uint4*)&table[(size_t)(1 + tok0 + row) * DD + n0 + off] = v;
    }
}

// ---------------- Kernel B: fp8 gather + max over F + dot(w2) + bias + mask ----------------
// One wave per token. Halves of the wave take alternating f-rows; uint2 (8 fp8) per lane.
// (Unchanged since round 3 for clean attribution.)
__global__ __launch_bounds__(256) void gather_score_kernel(
    const unsigned char* __restrict__ table,
    const int* __restrict__ select_idx,
    const int* __restrict__ word_mask,
    const float* __restrict__ w2,
    const float* __restrict__ b2,
    float* __restrict__ out)
{
    const int tid  = threadIdx.x;
    const int lane = tid & 63;
    const int wv   = tid >> 6;
    const int i    = blockIdx.x * 4 + wv;    // token
    const int half = lane >> 5;
    const int c    = lane & 31;
    const int d0   = c * 8;                  // 8 dims (8 B) per lane

    const int4* sp = (const int4*)(select_idx + (size_t)i * FF);
    int4 q0 = sp[0], q1 = sp[1];
    int rows[4];
    rows[0] = half ? q0.y : q0.x;
    rows[1] = half ? q0.w : q0.z;
    rows[2] = half ? q1.y : q1.x;
    rows[3] = half ? q1.w : q1.z;

    float m[8];
    #pragma unroll
    for (int j = 0; j < 8; ++j) m[j] = -INFINITY;

    #pragma unroll
    for (int it = 0; it < 4; ++it) {
        uint2 u = *(const uint2*)(table + (size_t)rows[it] * DD + d0);
        f32x2 a0 = __builtin_amdgcn_cvt_pk_f32_fp8(u.x, false);
        f32x2 a1 = __builtin_amdgcn_cvt_pk_f32_fp8(u.x, true);
        f32x2 a2 = __builtin_amdgcn_cvt_pk_f32_fp8(u.y, false);
        f32x2 a3 = __builtin_amdgcn_cvt_pk_f32_fp8(u.y, true);
        m[0] = fmaxf(m[0], a0.x); m[1] = fmaxf(m[1], a0.y);
        m[2] = fmaxf(m[2], a1.x); m[3] = fmaxf(m[3], a1.y);
        m[4] = fmaxf(m[4], a2.x); m[5] = fmaxf(m[5], a2.y);
        m[6] = fmaxf(m[6], a3.x); m[7] = fmaxf(m[7], a3.y);
    }

    #pragma unroll
    for (int j = 0; j < 8; ++j) m[j] = fmaxf(m[j], __shfl_xor(m[j], 32));

    f32x4 wa = *(const f32x4*)&w2[d0];
    f32x4 wb = *(const f32x4*)&w2[d0 + 4];
    float p = m[0] * wa.x + m[1] * wa.y + m[2] * wa.z + m[3] * wa.w
            + m[4] * wb.x + m[5] * wb.y + m[6] * wb.z + m[7] * wb.w;

    #pragma unroll
    for (int off = 16; off; off >>= 1) p += __shfl_xor(p, off);

    if (lane == 0) {
        float neg = word_mask[i] ? 0.f : -10000.f;
        out[i] = p + b2[0] + neg;
    }
}

extern "C" void kernel_launch(void* const* d_in, const int* in_sizes, int n_in,
                              void* d_out, int out_size, void* d_ws, size_t ws_size,
                              hipStream_t stream) {
    const float* hs    = (const float*)d_in[0];   // [B,S,D] f32
    const int*   sidx  = (const int*)  d_in[1];   // [B,S,F] i32
    const int*   wmask = (const int*)  d_in[2];   // [B,S]   i32
    const float* W1    = (const float*)d_in[3];   // [D,D]   f32
    const float* b1    = (const float*)d_in[4];   // [D]     f32
    const float* w2    = (const float*)d_in[5];   // [D]     f32
    const float* b2    = (const float*)d_in[6];   // [1]     f32
    float* out = (float*)d_out;                   // [B,S]   f32

    unsigned char* table = (unsigned char*)d_ws;  // [1+NTOK, D] fp8 e4m3 (~4.2 MB)

    gemm_tanh_kernel<<<(NTOK / BM) * (DD / BN), 512, 0, stream>>>(hs, W1, b1, table);
    gather_score_kernel<<<NTOK / 4, 256, 0, stream>>>(table, sidx, wmask, w2, b2, out);
}

// Round 7
// 87.714 us; speedup vs baseline: 1.1546x; 1.0074x over previous
//
#include <hip/hip_runtime.h>
#include <hip/hip_bf16.h>
#include <math.h>

// Problem constants
#define BB 8
#define SS 2048
#define DD 256
#define FF 8
#define NTOK (BB*SS)   // 16384

typedef __bf16 bf16x8 __attribute__((ext_vector_type(8)));
typedef float  f32x4  __attribute__((ext_vector_type(4)));
typedef float  f32x2  __attribute__((ext_vector_type(2)));

// ---------------- Kernel A: h = tanh(x @ W1^T + b1) -> fp8(e4m3) table via MFMA ----------
// R4 pipeline at half block size: BM=64 x BN=64, 256 threads (4 waves), grid 1024
// = 4 blocks/CU (same 16 waves/CU as R4 but 4 staggered barrier groups, shorter
// per-block load chains). K=256 in 4 steps of BK=64, double-buffered LDS, one
// barrier per step. XCD swizzle: n-siblings of a token group differ by 256 -> same XCD.
#define BM 64
#define BN 64
#define BK 64
#define NSTEP (DD/BK)   // 4
#define XS 72           // LDS row stride in ushorts (BK + 8 pad): 144 B, 16B-aligned

__device__ __forceinline__ float fast_tanh(float x) {
    float e = __expf(2.0f * x);
    return 1.0f - 2.0f * __builtin_amdgcn_rcpf(e + 1.0f);
}

__device__ __forceinline__ unsigned pack2_bf16(float a, float b) {
    return (__float_as_uint(a) >> 16) | (__float_as_uint(b) & 0xFFFF0000u);
}

__device__ __forceinline__ unsigned char f32_to_fp8(float v) {
    return (unsigned char)(__builtin_amdgcn_cvt_pk_fp8_f32(v, v, 0, false) & 0xFF);
}

__global__ __launch_bounds__(256, 4) void gemm_tanh_kernel(
    const float* __restrict__ x, const float* __restrict__ W1,
    const float* __restrict__ b1, unsigned char* __restrict__ table)
{
    __shared__ __align__(16) unsigned short xs[2][BM * XS];   // 18.4 KB (reused as fp8 scratch)
    __shared__ __align__(16) unsigned short wsb[2][BN * XS];  // 18.4 KB

    const int tid  = threadIdx.x;
    const int bx   = blockIdx.x;
    const int tokgrp = bx & 255;          // siblings (same x-tile) differ by 256 -> same XCD
    const int nblk   = bx >> 8;
    const int tok0 = tokgrp * BM;
    const int n0   = nblk * BN;

    // re-zero padding row 0 (256 fp8 bytes); ws is re-poisoned before every launch
    if (bx == 0 && tid < 64) ((unsigned int*)table)[tid] = 0u;

    const int wave = tid >> 6, lane = tid & 63;
    const int wm = wave >> 1;        // 0..1: 32-row m band
    const int wn = wave & 1;         // 0..1: 32-col n band
    const int lr = lane & 15;
    const int kg = lane >> 4;

    f32x4 xr[2], wr[2];              // staging registers (x and W1 k-slices)

    auto load_chunk = [&](int k0) {
        #pragma unroll
        for (int rep = 0; rep < 2; ++rep) {            // x: 64 rows x 16 f32x4 = 1024 slots... 2 reps x 2
            int slot = rep * 512 + (tid << 1);         // each thread takes 2 adjacent slots
            int row = slot >> 4, kc = slot & 15;
            xr[rep] = *(const f32x4*)&x[(size_t)(tok0 + row) * DD + k0 + kc * 4];
            // second adjacent slot handled below in wr-independent fashion
        }
        // NOTE: adjacent-slot trick replaced by plain 4-rep layout for clarity/coalescing:
        #pragma unroll
        for (int rep = 0; rep < 2; ++rep) {            // W1: 64 rows x 16 f32x4 = 1024 slots (2 of 4 reps)
            int slot = rep * 512 + (tid << 1);
            int row = slot >> 4, kc = slot & 15;
            wr[rep] = *(const f32x4*)&W1[(size_t)(n0 + row) * DD + k0 + kc * 4];
        }
    };
    // second halves of each tile (the other 2 reps), kept in separate regs to
    // limit live staging pressure
    f32x4 xr2[2], wr2[2];
    auto load_chunk2 = [&](int k0) {
        #pragma unroll
        for (int rep = 0; rep < 2; ++rep) {
            int slot = rep * 512 + (tid << 1) + 1;
            int row = slot >> 4, kc = slot & 15;
            xr2[rep] = *(const f32x4*)&x[(size_t)(tok0 + row) * DD + k0 + kc * 4];
        }
        #pragma unroll
        for (int rep = 0; rep < 2; ++rep) {
            int slot = rep * 512 + (tid << 1) + 1;
            int row = slot >> 4, kc = slot & 15;
            wr2[rep] = *(const f32x4*)&W1[(size_t)(n0 + row) * DD + k0 + kc * 4];
        }
    };
    auto store_lds = [&](int buf) {
        #pragma unroll
        for (int rep = 0; rep < 2; ++rep) {
            int slot = rep * 512 + (tid << 1);
            int row = slot >> 4, kc = slot & 15;
            uint2 p;
            p.x = pack2_bf16(xr[rep].x, xr[rep].y);
            p.y = pack2_bf16(xr[rep].z, xr[rep].w);
            *(uint2*)&xs[buf][row * XS + kc * 4] = p;
            int slot2 = slot + 1;
            int row2 = slot2 >> 4, kc2 = slot2 & 15;
            uint2 q;
            q.x = pack2_bf16(xr2[rep].x, xr2[rep].y);
            q.y = pack2_bf16(xr2[rep].z, xr2[rep].w);
            *(uint2*)&xs[buf][row2 * XS + kc2 * 4] = q;
        }
        #pragma unroll
        for (int rep = 0; rep < 2; ++rep) {
            int slot = rep * 512 + (tid << 1);
            int row = slot >> 4, kc = slot & 15;
            uint2 p;
            p.x = pack2_bf16(wr[rep].x, wr[rep].y);
            p.y = pack2_bf16(wr[rep].z, wr[rep].w);
            *(uint2*)&wsb[buf][row * XS + kc * 4] = p;
            int slot2 = slot + 1;
            int row2 = slot2 >> 4, kc2 = slot2 & 15;
            uint2 q;
            q.x = pack2_bf16(wr2[rep].x, wr2[rep].y);
            q.y = pack2_bf16(wr2[rep].z, wr2[rep].w);
            *(uint2*)&wsb[buf][row2 * XS + kc2 * 4] = q;
        }
    };

    f32x4 acc[2][2];
    #pragma unroll
    for (int mf = 0; mf < 2; ++mf)
        #pragma unroll
        for (int nf = 0; nf < 2; ++nf)
            acc[mf][nf] = (f32x4){0.f, 0.f, 0.f, 0.f};

    load_chunk(0);
    load_chunk2(0);
    store_lds(0);

    for (int s = 0; s < NSTEP; ++s) {
        __syncthreads();                               // one barrier per step
        const int buf = s & 1;
        if (s + 1 < NSTEP) { load_chunk((s + 1) * BK); load_chunk2((s + 1) * BK); }

        bf16x8 af[2][2], bfr[2][2];                    // [k-chunk][frag]
        #pragma unroll
        for (int c = 0; c < 2; ++c) {
            #pragma unroll
            for (int mf = 0; mf < 2; ++mf) {
                int m = wm * 32 + mf * 16 + lr;
                af[c][mf] = *(const bf16x8*)&xs[buf][m * XS + c * 32 + kg * 8];
            }
            #pragma unroll
            for (int nf = 0; nf < 2; ++nf) {
                int n = wn * 32 + nf * 16 + lr;
                bfr[c][nf] = *(const bf16x8*)&wsb[buf][n * XS + c * 32 + kg * 8];
            }
        }
        if (s + 1 < NSTEP) store_lds(buf ^ 1);         // buf^1 reads drained at this barrier

        #pragma unroll
        for (int c = 0; c < 2; ++c)
            #pragma unroll
            for (int mf = 0; mf < 2; ++mf)
                #pragma unroll
                for (int nf = 0; nf < 2; ++nf)
                    acc[mf][nf] = __builtin_amdgcn_mfma_f32_16x16x32_bf16(
                        af[c][mf], bfr[c][nf], acc[mf][nf], 0, 0, 0);
    }

    // ---- epilogue: bias + tanh -> fp8, LDS transpose, coalesced uint4 stores ----
    float bj[2];
    #pragma unroll
    for (int nf = 0; nf < 2; ++nf) bj[nf] = b1[n0 + wn * 32 + nf * 16 + lr];

    __syncthreads();                                   // safe to reuse xs as scratch
    unsigned char* sc = (unsigned char*)&xs[0][0];     // [BM][80] fp8 scratch (5.1 KB)
    #pragma unroll
    for (int mf = 0; mf < 2; ++mf) {
        #pragma unroll
        for (int r = 0; r < 4; ++r) {
            int m = wm * 32 + mf * 16 + kg * 4 + r;    // C/D layout: col=lane&15, row=kg*4+reg
            #pragma unroll
            for (int nf = 0; nf < 2; ++nf) {
                float v = fast_tanh(acc[mf][nf][r] + bj[nf]);
                sc[m * 80 + wn * 32 + nf * 16 + lr] = f32_to_fp8(v);
            }
        }
    }
    __syncthreads();
    {
        int row = tid >> 2;                            // 64 rows x 64 B, 16 B per thread
        int off = (tid & 3) * 16;
        uint4 v = *(const uint4*)&sc[row * 80 + off];
        *(uint4*)&table[(size_t)(1 + tok0 + row) * DD + n0 + off] = v;
    }
}

// ---------------- Kernel B: fp8 gather + max over F + dot(w2) + bias + mask ----------------
// One wave per token. Halves of the wave take alternating f-rows; uint2 (8 fp8) per lane.
// (Unchanged since round 3 for clean attribution.)
__global__ __launch_bounds__(256) void gather_score_kernel(
    const unsigned char* __restrict__ table,
    const int* __restrict__ select_idx,
    const int* __restrict__ word_mask,
    const float* __restrict__ w2,
    const float* __restrict__ b2,
    float* __restrict__ out)
{
    const int tid  = threadIdx.x;
    const int lane = tid & 63;
    const int wv   = tid >> 6;
    const int i    = blockIdx.x * 4 + wv;    // token
    const int half = lane >> 5;
    const int c    = lane & 31;
    const int d0   = c * 8;                  // 8 dims (8 B) per lane

    const int4* sp = (const int4*)(select_idx + (size_t)i * FF);
    int4 q0 = sp[0], q1 = sp[1];
    int rows[4];
    rows[0] = half ? q0.y : q0.x;
    rows[1] = half ? q0.w : q0.z;
    rows[2] = half ? q1.y : q1.x;
    rows[3] = half ? q1.w : q1.z;

    float m[8];
    #pragma unroll
    for (int j = 0; j < 8; ++j) m[j] = -INFINITY;

    #pragma unroll
    for (int it = 0; it < 4; ++it) {
        uint2 u = *(const uint2*)(table + (size_t)rows[it] * DD + d0);
        f32x2 a0 = __builtin_amdgcn_cvt_pk_f32_fp8(u.x, false);
        f32x2 a1 = __builtin_amdgcn_cvt_pk_f32_fp8(u.x, true);
        f32x2 a2 = __builtin_amdgcn_cvt_pk_f32_fp8(u.y, false);
        f32x2 a3 = __builtin_amdgcn_cvt_pk_f32_fp8(u.y, true);
        m[0] = fmaxf(m[0], a0.x); m[1] = fmaxf(m[1], a0.y);
        m[2] = fmaxf(m[2], a1.x); m[3] = fmaxf(m[3], a1.y);
        m[4] = fmaxf(m[4], a2.x); m[5] = fmaxf(m[5], a2.y);
        m[6] = fmaxf(m[6], a3.x); m[7] = fmaxf(m[7], a3.y);
    }

    #pragma unroll
    for (int j = 0; j < 8; ++j) m[j] = fmaxf(m[j], __shfl_xor(m[j], 32));

    f32x4 wa = *(const f32x4*)&w2[d0];
    f32x4 wb = *(const f32x4*)&w2[d0 + 4];
    float p = m[0] * wa.x + m[1] * wa.y + m[2] * wa.z + m[3] * wa.w
            + m[4] * wb.x + m[5] * wb.y + m[6] * wb.z + m[7] * wb.w;

    #pragma unroll
    for (int off = 16; off; off >>= 1) p += __shfl_xor(p, off);

    if (lane == 0) {
        float neg = word_mask[i] ? 0.f : -10000.f;
        out[i] = p + b2[0] + neg;
    }
}

extern "C" void kernel_launch(void* const* d_in, const int* in_sizes, int n_in,
                              void* d_out, int out_size, void* d_ws, size_t ws_size,
                              hipStream_t stream) {
    const float* hs    = (const float*)d_in[0];   // [B,S,D] f32
    const int*   sidx  = (const int*)  d_in[1];   // [B,S,F] i32
    const int*   wmask = (const int*)  d_in[2];   // [B,S]   i32
    const float* W1    = (const float*)d_in[3];   // [D,D]   f32
    const float* b1    = (const float*)d_in[4];   // [D]     f32
    const float* w2    = (const float*)d_in[5];   // [D]     f32
    const float* b2    = (const float*)d_in[6];   // [1]     f32
    float* out = (float*)d_out;                   // [B,S]   f32

    unsigned char* table = (unsigned char*)d_ws;  // [1+NTOK, D] fp8 e4m3 (~4.2 MB)

    gemm_tanh_kernel<<<(NTOK / BM) * (DD / BN), 256, 0, stream>>>(hs, W1, b1, table);
    gather_score_kernel<<<NTOK / 4, 256, 0, stream>>>(table, sidx, wmask, w2, b2, out);
}

// Round 8
// 85.678 us; speedup vs baseline: 1.1820x; 1.0238x over previous
//
#include <hip/hip_runtime.h>
#include <hip/hip_bf16.h>
#include <math.h>

// Problem constants
#define BB 8
#define SS 2048
#define DD 256
#define FF 8
#define NTOK (BB*SS)   // 16384

typedef __bf16 bf16x8 __attribute__((ext_vector_type(8)));
typedef float  f32x4  __attribute__((ext_vector_type(4)));
typedef float  f32x2  __attribute__((ext_vector_type(2)));

// ---------------- Kernel A: h = tanh(x @ W1^T + b1) -> fp8(e4m3) table via MFMA ----------
// R4 structure (best measured: 85.8 us total). BM=128 x BN=64, 512 threads (8 waves),
// grid 512 = 2 blocks/CU. K=256 in 4 steps of BK=64, double-buffered LDS, ONE barrier
// per step. XCD swizzle: the 4 n-siblings of a token group share an XCD.
// [session note] R5 (W1 in regs) spilled: -15.5us. R6 (W1 once in LDS) and R7
// (64x64 blocks) both neutral-to-worse. A's structure is exhausted; floor ~11.3us
// (64 MB fp32 x-read), measured ~15us.
#define BM 128
#define BN 64
#define BK 64
#define NSTEP (DD/BK)   // 4
#define XS 72           // LDS row stride in ushorts (BK + 8 pad): 144 B, 16B-aligned

__device__ __forceinline__ float fast_tanh(float x) {
    float e = __expf(2.0f * x);
    return 1.0f - 2.0f * __builtin_amdgcn_rcpf(e + 1.0f);
}

__device__ __forceinline__ unsigned pack2_bf16(float a, float b) {
    return (__float_as_uint(a) >> 16) | (__float_as_uint(b) & 0xFFFF0000u);
}

__device__ __forceinline__ unsigned char f32_to_fp8(float v) {
    return (unsigned char)(__builtin_amdgcn_cvt_pk_fp8_f32(v, v, 0, false) & 0xFF);
}

__global__ __launch_bounds__(512, 4) void gemm_tanh_kernel(
    const float* __restrict__ x, const float* __restrict__ W1,
    const float* __restrict__ b1, unsigned char* __restrict__ table)
{
    __shared__ __align__(16) unsigned short xs[2][BM * XS];   // 36 KB (reused as fp8 scratch)
    __shared__ __align__(16) unsigned short wsb[2][BN * XS];  // 18 KB

    const int tid  = threadIdx.x;
    const int bx   = blockIdx.x;
    const int tokgrp = bx & 127;          // same-XCD for the 4 n-blocks of a token group
    const int nblk   = bx >> 7;
    const int tok0 = tokgrp * BM;
    const int n0   = nblk * BN;

    // re-zero padding row 0 (256 fp8 bytes); ws is re-poisoned before every launch
    if (bx == 0 && tid < 64) ((unsigned int*)table)[tid] = 0u;

    const int wave = tid >> 6, lane = tid & 63;
    const int wm = wave >> 1;        // 0..3: 32-row m band
    const int wn = wave & 1;         // 0..1: 32-col n band
    const int lr = lane & 15;
    const int kg = lane >> 4;

    f32x4 xr[4], wr[2];              // staging registers

    auto load_chunk = [&](int k0) {
        #pragma unroll
        for (int rep = 0; rep < 4; ++rep) {            // x: 128 rows x 16 f32x4 = 2048 slots
            int slot = rep * 512 + tid;
            int row = slot >> 4, kc = slot & 15;
            xr[rep] = *(const f32x4*)&x[(size_t)(tok0 + row) * DD + k0 + kc * 4];
        }
        #pragma unroll
        for (int rep = 0; rep < 2; ++rep) {            // W1: 64 rows x 16 f32x4 = 1024 slots
            int slot = rep * 512 + tid;
            int row = slot >> 4, kc = slot & 15;
            wr[rep] = *(const f32x4*)&W1[(size_t)(n0 + row) * DD + k0 + kc * 4];
        }
    };
    auto store_lds = [&](int buf) {
        #pragma unroll
        for (int rep = 0; rep < 4; ++rep) {
            int slot = rep * 512 + tid;
            int row = slot >> 4, kc = slot & 15;
            uint2 p;
            p.x = pack2_bf16(xr[rep].x, xr[rep].y);
            p.y = pack2_bf16(xr[rep].z, xr[rep].w);
            *(uint2*)&xs[buf][row * XS + kc * 4] = p;
        }
        #pragma unroll
        for (int rep = 0; rep < 2; ++rep) {
            int slot = rep * 512 + tid;
            int row = slot >> 4, kc = slot & 15;
            uint2 p;
            p.x = pack2_bf16(wr[rep].x, wr[rep].y);
            p.y = pack2_bf16(wr[rep].z, wr[rep].w);
            *(uint2*)&wsb[buf][row * XS + kc * 4] = p;
        }
    };

    f32x4 acc[2][2];
    #pragma unroll
    for (int mf = 0; mf < 2; ++mf)
        #pragma unroll
        for (int nf = 0; nf < 2; ++nf)
            acc[mf][nf] = (f32x4){0.f, 0.f, 0.f, 0.f};

    load_chunk(0);
    store_lds(0);

    for (int s = 0; s < NSTEP; ++s) {
        __syncthreads();                               // one barrier per step
        const int buf = s & 1;
        if (s + 1 < NSTEP) load_chunk((s + 1) * BK);   // global loads in flight early

        bf16x8 af[2][2], bfr[2][2];                    // [k-chunk][frag]
        #pragma unroll
        for (int c = 0; c < 2; ++c) {
            #pragma unroll
            for (int mf = 0; mf < 2; ++mf) {
                int m = wm * 32 + mf * 16 + lr;
                af[c][mf] = *(const bf16x8*)&xs[buf][m * XS + c * 32 + kg * 8];
            }
            #pragma unroll
            for (int nf = 0; nf < 2; ++nf) {
                int n = wn * 32 + nf * 16 + lr;
                bfr[c][nf] = *(const bf16x8*)&wsb[buf][n * XS + c * 32 + kg * 8];
            }
        }
        if (s + 1 < NSTEP) store_lds(buf ^ 1);         // buf^1 reads drained at this step's barrier

        #pragma unroll
        for (int c = 0; c < 2; ++c)
            #pragma unroll
            for (int mf = 0; mf < 2; ++mf)
                #pragma unroll
                for (int nf = 0; nf < 2; ++nf)
                    acc[mf][nf] = __builtin_amdgcn_mfma_f32_16x16x32_bf16(
                        af[c][mf], bfr[c][nf], acc[mf][nf], 0, 0, 0);
    }

    // ---- epilogue: bias + tanh -> fp8, LDS transpose, coalesced uint4 stores ----
    float bj[2];
    #pragma unroll
    for (int nf = 0; nf < 2; ++nf) bj[nf] = b1[n0 + wn * 32 + nf * 16 + lr];

    __syncthreads();                                   // safe to reuse xs as scratch
    unsigned char* sc = (unsigned char*)&xs[0][0];     // [BM][80] fp8 scratch (10 KB)
    #pragma unroll
    for (int mf = 0; mf < 2; ++mf) {
        #pragma unroll
        for (int r = 0; r < 4; ++r) {
            int m = wm * 32 + mf * 16 + kg * 4 + r;    // C/D layout: col=lane&15, row=kg*4+reg
            #pragma unroll
            for (int nf = 0; nf < 2; ++nf) {
                float v = fast_tanh(acc[mf][nf][r] + bj[nf]);
                sc[m * 80 + wn * 32 + nf * 16 + lr] = f32_to_fp8(v);
            }
        }
    }
    __syncthreads();
    {
        int row = tid >> 2;                            // 128 rows x 64 B, 16 B per thread
        int off = (tid & 3) * 16;
        uint4 v = *(const uint4*)&sc[row * 80 + off];
        *(uint4*)&table[(size_t)(1 + tok0 + row) * DD + n0 + off] = v;
    }
}

// ---------------- Kernel B: fp8 gather + max over F + dot(w2) + bias + mask ----------------
// One wave per token. Halves of the wave take alternating f-rows; uint2 (8 fp8) per lane.
// (Unchanged since round 3.)
__global__ __launch_bounds__(256) void gather_score_kernel(
    const unsigned char* __restrict__ table,
    const int* __restrict__ select_idx,
    const int* __restrict__ word_mask,
    const float* __restrict__ w2,
    const float* __restrict__ b2,
    float* __restrict__ out)
{
    const int tid  = threadIdx.x;
    const int lane = tid & 63;
    const int wv   = tid >> 6;
    const int i    = blockIdx.x * 4 + wv;    // token
    const int half = lane >> 5;
    const int c    = lane & 31;
    const int d0   = c * 8;                  // 8 dims (8 B) per lane

    const int4* sp = (const int4*)(select_idx + (size_t)i * FF);
    int4 q0 = sp[0], q1 = sp[1];
    int rows[4];
    rows[0] = half ? q0.y : q0.x;
    rows[1] = half ? q0.w : q0.z;
    rows[2] = half ? q1.y : q1.x;
    rows[3] = half ? q1.w : q1.z;

    float m[8];
    #pragma unroll
    for (int j = 0; j < 8; ++j) m[j] = -INFINITY;

    #pragma unroll
    for (int it = 0; it < 4; ++it) {
        uint2 u = *(const uint2*)(table + (size_t)rows[it] * DD + d0);
        f32x2 a0 = __builtin_amdgcn_cvt_pk_f32_fp8(u.x, false);
        f32x2 a1 = __builtin_amdgcn_cvt_pk_f32_fp8(u.x, true);
        f32x2 a2 = __builtin_amdgcn_cvt_pk_f32_fp8(u.y, false);
        f32x2 a3 = __builtin_amdgcn_cvt_pk_f32_fp8(u.y, true);
        m[0] = fmaxf(m[0], a0.x); m[1] = fmaxf(m[1], a0.y);
        m[2] = fmaxf(m[2], a1.x); m[3] = fmaxf(m[3], a1.y);
        m[4] = fmaxf(m[4], a2.x); m[5] = fmaxf(m[5], a2.y);
        m[6] = fmaxf(m[6], a3.x); m[7] = fmaxf(m[7], a3.y);
    }

    #pragma unroll
    for (int j = 0; j < 8; ++j) m[j] = fmaxf(m[j], __shfl_xor(m[j], 32));

    f32x4 wa = *(const f32x4*)&w2[d0];
    f32x4 wb = *(const f32x4*)&w2[d0 + 4];
    float p = m[0] * wa.x + m[1] * wa.y + m[2] * wa.z + m[3] * wa.w
            + m[4] * wb.x + m[5] * wb.y + m[6] * wb.z + m[7] * wb.w;

    #pragma unroll
    for (int off = 16; off; off >>= 1) p += __shfl_xor(p, off);

    if (lane == 0) {
        float neg = word_mask[i] ? 0.f : -10000.f;
        out[i] = p + b2[0] + neg;
    }
}

extern "C" void kernel_launch(void* const* d_in, const int* in_sizes, int n_in,
                              void* d_out, int out_size, void* d_ws, size_t ws_size,
                              hipStream_t stream) {
    const float* hs    = (const float*)d_in[0];   // [B,S,D] f32
    const int*   sidx  = (const int*)  d_in[1];   // [B,S,F] i32
    const int*   wmask = (const int*)  d_in[2];   // [B,S]   i32
    const float* W1    = (const float*)d_in[3];   // [D,D]   f32
    const float* b1    = (const float*)d_in[4];   // [D]     f32
    const float* w2    = (const float*)d_in[5];   // [D]     f32
    const float* b2    = (const float*)d_in[6];   // [1]     f32
    float* out = (float*)d_out;                   // [B,S]   f32

    unsigned char* table = (unsigned char*)d_ws;  // [1+NTOK, D] fp8 e4m3 (~4.2 MB)

    gemm_tanh_kernel<<<(NTOK / BM) * (DD / BN), 512, 0, stream>>>(hs, W1, b1, table);
    gather_score_kernel<<<NTOK / 4, 256, 0, stream>>>(table, sidx, wmask, w2, b2, out);
}